// Round 17
// baseline (130.069 us; speedup 1.0000x reference)
//
#include <hip/hip_runtime.h>
#include <stdint.h>

typedef unsigned short u16;
typedef __attribute__((ext_vector_type(8))) short short8;
typedef __attribute__((ext_vector_type(8))) unsigned short ushort8v;
typedef __attribute__((ext_vector_type(4))) float f32x4;

#define B_  4
#define T_  2048
#define E_  1024
#define H_  16
#define D_  64
#define HD_ 1024
#define BT_ (B_*T_)
#define TC_ 64                 // scan chunk length
#define NC_ (T_/TC_)           // 32 chunks
#define SG_ 32                 // score e-groups (SEB = E/SG = 32)
#define SEB_ (E_/SG_)
#define SHB_ 1                 // h's per score block -> 4096 score blocks

__device__ __forceinline__ u16 f2b(float f) {
  uint32_t u = __float_as_uint(f);
  uint32_t r = (u + 0x7FFFu + ((u >> 16) & 1u)) >> 16;   // RNE, inputs never NaN
  return (u16)r;
}
__device__ __forceinline__ float b2f(u16 u) {
  return __uint_as_float(((uint32_t)u) << 16);
}

// ---------------------------------------------------------------------------
// P: fused prep. blocks [0,2048): x -> xb bf16 + xTb8 (x^T in [b][e/8][t][8e]).
// blocks [2048,2560): the two 1024x1024 weight transposes (f32 -> bf16^T).
// ---------------------------------------------------------------------------
__global__ __launch_bounds__(256) void prep_all(const float* __restrict__ x,
                                                const float* __restrict__ wv,
                                                const float* __restrict__ wo,
                                                u16* __restrict__ xb,
                                                u16* __restrict__ xTb8,
                                                u16* __restrict__ wvT,
                                                u16* __restrict__ woT) {
  __shared__ float tile[64][65];
  const int bid = blockIdx.x;
  if (bid < 2048) {
    const int b = bid >> 9, rest = bid & 511;
    const int t0 = (rest >> 4) * 64, e0 = (rest & 15) * 64;
    const int c4 = (threadIdx.x & 15) * 4;    // 0..60
    const int rw = threadIdx.x >> 4;          // 0..15
#pragma unroll
    for (int r = 0; r < 4; ++r) {
      const int row = r * 16 + rw;            // t-local
      const float4 v4 = *reinterpret_cast<const float4*>(
          &x[((size_t)b * T_ + t0 + row) * E_ + e0 + c4]);
      tile[row][c4 + 0] = v4.x; tile[row][c4 + 1] = v4.y;
      tile[row][c4 + 2] = v4.z; tile[row][c4 + 3] = v4.w;
      ushort4 o;
      o.x = f2b(v4.x); o.y = f2b(v4.y); o.z = f2b(v4.z); o.w = f2b(v4.w);
      *reinterpret_cast<ushort4*>(&xb[((size_t)(b * T_ + t0 + row)) * E_ + e0 + c4]) = o;
    }
    __syncthreads();
    const int tl = threadIdx.x & 63;          // t-local
    const int eg = threadIdx.x >> 6;          // 0..3
#pragma unroll
    for (int p = 0; p < 2; ++p) {
      const int egg = eg + p * 4;             // e-group 0..7 (8 e's each)
      ushort8v o;
#pragma unroll
      for (int j = 0; j < 8; ++j) o[j] = f2b(tile[tl][egg * 8 + j]);
      *reinterpret_cast<ushort8v*>(
          &xTb8[((size_t)(b * (E_ / 8) + (e0 >> 3) + egg) * T_ + t0 + tl) * 8]) = o;
    }
  } else {
    const int k = bid - 2048;
    const float* in = (k >> 8) ? wo : wv;
    u16* out = (k >> 8) ? woT : wvT;
    const int r0 = ((k >> 4) & 15) * 64, c0 = (k & 15) * 64;
    const int tx = threadIdx.x & 63, ty = threadIdx.x >> 6;
#pragma unroll
    for (int r = 0; r < 16; ++r) {
      int row = r * 4 + ty;
      tile[row][tx] = in[(size_t)(r0 + row) * 1024 + c0 + tx];
    }
    __syncthreads();
#pragma unroll
    for (int r = 0; r < 16; ++r) {
      int row = r * 4 + ty;
      out[(size_t)(c0 + row) * 1024 + r0 + tx] = f2b(tile[tx][row]);
    }
  }
}

// ---------------------------------------------------------------------------
// GEMM: C[M][N] = A[M][K] * Bt[N][K]^T, bf16 in, f32 accum.
// R13 dbuf schedule at BK=32: 2-slot LDS = 32 KB total -> ~4 blocks/CU
// (was 64 KB / 2 blocks). STAGE(kt+1) issued BEFORE ds_read+MFMA of kt; one
// __syncthreads per K-step. 64B-row bank swizzle (R15-verified addressing:
// source granule g^((row>>1)&3), read granule l4^((l15>>1)&3)), gload_lds
// w16, XCD swizzle, setprio. Per step: 4 gload_lds, 8 ds_read_b128, 16 MFMA.
// ---------------------------------------------------------------------------
template <int OUT_BF16>
__global__ __launch_bounds__(256) void gemm_bt(const u16* __restrict__ A,
                                               const u16* __restrict__ Bt,
                                               float* __restrict__ Cf,
                                               u16* __restrict__ Cb,
                                               int M, int N, int K) {
  __shared__ __align__(16) u16 As[2][128 * 32];   // 8 KB each
  __shared__ __align__(16) u16 Bs[2][128 * 32];
  const int tid  = threadIdx.x;
  const int lane = tid & 63;
  const int wave = tid >> 6;
  const int wr_  = wave >> 1, wc_ = wave & 1;

  const int nwg = gridDim.x * gridDim.y;
  const int bid = blockIdx.y * gridDim.x + blockIdx.x;
  const int cpx = nwg >> 3;
  const int swz = (bid & 7) * cpx + (bid >> 3);
  const int bx = swz % gridDim.x, by = swz / gridDim.x;
  const int brow = by * 128;
  const int bcol = bx * 128;
  const int l15 = lane & 15, l4 = lane >> 4;

  f32x4 acc[4][4];
  const f32x4 zero = {0.f, 0.f, 0.f, 0.f};
#pragma unroll
  for (int i = 0; i < 4; ++i)
#pragma unroll
    for (int j = 0; j < 4; ++j) acc[i][j] = zero;

  // stage K-tile kt (A,B: 128x32 each) into buffer buf. 4 gload_lds/thread.
  auto stage = [&](int kt, int buf) {
    const int k0 = kt * 32;
#pragma unroll
    for (int s2 = 0; s2 < 2; ++s2) {
      const int c = s2 * 256 + tid;             // granule id 0..511
      const int row = c >> 2, g = c & 3;        // 4 granules per 64B row
      const int gs = g ^ ((row >> 1) & 3);      // inverse-swizzled SOURCE granule
      const u16* ga = A  + (size_t)(brow + row) * K + k0 + gs * 8;
      const u16* gb = Bt + (size_t)(bcol + row) * K + k0 + gs * 8;
      u16* la = &As[buf][(size_t)(s2 * 256 + wave * 64) * 8];  // wave-uniform base
      u16* lb = &Bs[buf][(size_t)(s2 * 256 + wave * 64) * 8];
      __builtin_amdgcn_global_load_lds((const __attribute__((address_space(1))) void*)ga,
                                       (__attribute__((address_space(3))) void*)la,
                                       16, 0, 0);
      __builtin_amdgcn_global_load_lds((const __attribute__((address_space(1))) void*)gb,
                                       (__attribute__((address_space(3))) void*)lb,
                                       16, 0, 0);
    }
  };

  const int sgr = l4 ^ ((l15 >> 1) & 3);        // swizzled read granule

  const int NK = K / 32;                        // 32
  stage(0, 0);
  __syncthreads();                              // buf0 ready

  int cur = 0;
  for (int kt = 0; kt < NK; ++kt) {
    if (kt + 1 < NK) stage(kt + 1, cur ^ 1);    // issue next tile FIRST

    short8 af[4], bfr[4];
#pragma unroll
    for (int mi = 0; mi < 4; ++mi)
      af[mi] = *reinterpret_cast<const short8*>(
          &As[cur][((wr_ * 64 + mi * 16 + l15) * 4 + sgr) * 8]);
#pragma unroll
    for (int ni = 0; ni < 4; ++ni)
      bfr[ni] = *reinterpret_cast<const short8*>(
          &Bs[cur][((wc_ * 64 + ni * 16 + l15) * 4 + sgr) * 8]);

    __builtin_amdgcn_s_setprio(1);
#pragma unroll
    for (int mi = 0; mi < 4; ++mi)
#pragma unroll
      for (int ni = 0; ni < 4; ++ni)
        acc[mi][ni] = __builtin_amdgcn_mfma_f32_16x16x32_bf16(af[mi], bfr[ni],
                                                              acc[mi][ni], 0, 0, 0);
    __builtin_amdgcn_s_setprio(0);
    __syncthreads();                            // drains vmcnt -> next buf ready;
    cur ^= 1;                                   // also protects buf[cur] reuse
  }

#pragma unroll
  for (int mi = 0; mi < 4; ++mi) {
#pragma unroll
    for (int ni = 0; ni < 4; ++ni) {
      const int col = bcol + wc_ * 64 + ni * 16 + l15;
#pragma unroll
      for (int j = 0; j < 4; ++j) {
        const int row = brow + wr_ * 64 + mi * 16 + l4 * 4 + j;
        if (OUT_BF16) Cb[(size_t)row * N + col] = f2b(acc[mi][ni][j]);
        else          Cf[(size_t)row * N + col] = acc[mi][ni][j];
      }
    }
  }
}

// ---------------------------------------------------------------------------
// K2a: partial[g][b][h][t] (bf16) = sum_{e in g} x[b,t,e]*wr[h,e,t] / 8.
// SHB=1 -> 4096 blocks (16/CU TLP for the 128MB wr stream). XCD-coherent
// decode: 16 h-blocks sharing an xTb8 slice are adjacent on one XCD.
// ---------------------------------------------------------------------------
__global__ __launch_bounds__(256) void score_partial(const u16* __restrict__ xTb8,
                                                     const float* __restrict__ wr,
                                                     u16* __restrict__ partial) {
  const int lid    = blockIdx.x;                // 0..4095
  const int xcd    = lid & 7;
  const int within = lid >> 3;                  // 0..511
  const int hz     = within & 15;               // 0..15 (adjacent per (t,g))
  const int pair   = xcd * 32 + (within >> 4);  // 0..255, XCD-exclusive
  const int t  = (pair >> 5) * 256 + threadIdx.x;
  const int g  = pair & 31;
  const int h0 = hz;                            // SHB_ == 1

  float acc[4];                                 // [b]
#pragma unroll
  for (int b = 0; b < 4; ++b) acc[b] = 0.f;

#pragma unroll
  for (int e8 = 0; e8 < SEB_ / 8; ++e8) {       // 4 iters of 8 e's
    const int eb = g * (SEB_ / 8) + e8;         // e-group index
    ushort8v xv[4];
#pragma unroll
    for (int b = 0; b < 4; ++b)
      xv[b] = *reinterpret_cast<const ushort8v*>(
          &xTb8[((size_t)(b * (E_ / 8) + eb) * T_ + t) * 8]);
#pragma unroll
    for (int j = 0; j < 8; ++j) {
      const int e = eb * 8 + j;
      const float w = wr[((size_t)h0 * E_ + e) * T_ + t];
#pragma unroll
      for (int b = 0; b < 4; ++b) acc[b] = fmaf(b2f(xv[b][j]), w, acc[b]);
    }
  }
  u16* pp = partial + (size_t)g * (B_ * H_ * T_);
#pragma unroll
  for (int b = 0; b < 4; ++b)
    pp[((size_t)b * H_ + h0) * T_ + t] = f2b(acc[b] * 0.125f);
}

// ---------------------------------------------------------------------------
// K3a (fused reduce): lane t sums the 32 bf16 partials -> s value; writes s
// for chunk_scan; wave-local LDS broadcast. Then per-chunk max + sums.
// ---------------------------------------------------------------------------
__global__ __launch_bounds__(256) void chunk_sums(const u16* __restrict__ partial,
                                                  const u16* __restrict__ v,
                                                  float* __restrict__ s,
                                                  float* __restrict__ sev,
                                                  float* __restrict__ se,
                                                  float* __restrict__ mc) {
  const int bh = blockIdx.y;
  const int b = bh >> 4, h = bh & 15;
  const int w = threadIdx.x >> 6, d = threadIdx.x & 63;
  const int c = blockIdx.x * 4 + w;
  const int t = blockIdx.x * 256 + threadIdx.x;   // == c*64 + d

  float sv = 0.f;
#pragma unroll
  for (int g = 0; g < SG_; ++g)
    sv += b2f(partial[(size_t)g * (B_ * H_ * T_) + (size_t)bh * T_ + t]);
  s[(size_t)bh * T_ + t] = sv;

  __shared__ float es[4][64];
  es[w][d] = sv;                                  // wave-local, no barrier needed

  float lm = sv;                                  // chunk max
#pragma unroll
  for (int off = 1; off < 64; off <<= 1) lm = fmaxf(lm, __shfl_xor(lm, off, 64));

  const u16* vp = v + ((size_t)(b * T_ + c * TC_)) * HD_ + h * D_ + d;
  float acc = 0.f, ae = 0.f;
#pragma unroll 8
  for (int tt = 0; tt < TC_; ++tt) {
    float e = __expf(es[w][tt] - lm);
    acc = fmaf(e, b2f(vp[(size_t)tt * HD_]), acc);
    ae += e;
  }
  sev[((size_t)bh * NC_ + c) * D_ + d] = acc;
  if (d == 0) { se[bh * NC_ + c] = ae; mc[bh * NC_ + c] = lm; }
}

// ---------------------------------------------------------------------------
// K3c: global max; prefix from rescaled chunk totals; inclusive rescan.
// ---------------------------------------------------------------------------
__global__ __launch_bounds__(256) void chunk_scan(const float* __restrict__ s,
                                                  const u16* __restrict__ v,
                                                  const float* __restrict__ sev,
                                                  const float* __restrict__ se,
                                                  const float* __restrict__ mc,
                                                  u16* __restrict__ attn) {
  const int bh = blockIdx.y;
  const int b = bh >> 4, h = bh & 15;
  const int w = threadIdx.x >> 6, d = threadIdx.x & 63;
  const int c = blockIdx.x * 4 + w;
  const float* mcp = mc + bh * NC_;

  float gm = (d < NC_) ? mcp[d] : -1e30f;
#pragma unroll
  for (int off = 1; off < 64; off <<= 1) gm = fmaxf(gm, __shfl_xor(gm, off, 64));

  const float* sevp = sev + (size_t)bh * NC_ * D_;
  const float* sep  = se + bh * NC_;
  float pn = 0.f, pd = 0.f;
  for (int c2 = 0; c2 < c; ++c2) {
    float f = __expf(mcp[c2] - gm);
    pn = fmaf(sevp[(size_t)c2 * D_ + d], f, pn);
    pd = fmaf(sep[c2], f, pd);
  }

  const float* sp = s + (size_t)bh * T_ + c * TC_;
  const u16* vp = v + ((size_t)(b * T_ + c * TC_)) * HD_ + h * D_ + d;
  u16* ap = attn + ((size_t)(b * T_ + c * TC_)) * HD_ + h * D_ + d;
#pragma unroll 8
  for (int tt = 0; tt < TC_; ++tt) {
    float e = __expf(sp[tt] - gm);
    pn = fmaf(e, b2f(vp[(size_t)tt * HD_]), pn);
    pd += e;
    ap[(size_t)tt * HD_] = f2b(__fdividef(pn, pd));
  }
}

// ---------------------------------------------------------------------------
extern "C" void kernel_launch(void* const* d_in, const int* in_sizes, int n_in,
                              void* d_out, int out_size, void* d_ws, size_t ws_size,
                              hipStream_t stream) {
  const float* x  = (const float*)d_in[0];
  const float* wv = (const float*)d_in[1];
  const float* wr = (const float*)d_in[2];
  const float* wo = (const float*)d_in[3];
  float* out = (float*)d_out;

  char* ws = (char*)d_ws;
  size_t off = 0;
  auto alloc = [&](size_t bytes) {
    void* p = ws + off;
    off += (bytes + 255) & ~(size_t)255;
    return p;
  };
  u16*   xb   = (u16*)  alloc((size_t)BT_ * E_ * 2);
  u16*   xTb8 = (u16*)  alloc((size_t)B_ * E_ * T_ * 2);
  u16*   wvT  = (u16*)  alloc((size_t)HD_ * E_ * 2);
  u16*   woT  = (u16*)  alloc((size_t)E_ * HD_ * 2);
  u16*   vv   = (u16*)  alloc((size_t)BT_ * HD_ * 2);
  u16*   attn = (u16*)  alloc((size_t)BT_ * HD_ * 2);
  float* s    = (float*)alloc((size_t)B_ * H_ * T_ * 4);
  float* sev  = (float*)alloc((size_t)B_ * H_ * NC_ * D_ * 4);
  float* se   = (float*)alloc((size_t)B_ * H_ * NC_ * 4);
  float* mc   = (float*)alloc((size_t)B_ * H_ * NC_ * 4);
  u16*   part = (u16*)  alloc((size_t)SG_ * B_ * H_ * T_ * 2);   // 8 MB bf16

  prep_all<<<2560, 256, 0, stream>>>(x, wv, wo, xb, xTb8, wvT, woT);

  // v = xb @ wv  (bf16 out)
  gemm_bt<1><<<dim3(HD_ / 128, BT_ / 128), 256, 0, stream>>>(xb, wvT, nullptr, vv, BT_, HD_, E_);

  score_partial<<<4096, 256, 0, stream>>>(xTb8, wr, part);

  chunk_sums<<<dim3(NC_ / 4, B_ * H_), 256, 0, stream>>>(part, vv, s, sev, se, mc);
  chunk_scan<<<dim3(NC_ / 4, B_ * H_), 256, 0, stream>>>(s, vv, sev, se, mc, attn);

  // out = attn @ wo  (f32 out)
  gemm_bt<0><<<dim3(E_ / 128, BT_ / 128), 256, 0, stream>>>(attn, woT, out, nullptr, BT_, E_, HD_);
}

// Round 18
// 117.127 us; speedup vs baseline: 1.1105x; 1.1105x over previous
//
#include <hip/hip_runtime.h>
#include <stdint.h>

typedef unsigned short u16;
typedef __attribute__((ext_vector_type(8))) short short8;
typedef __attribute__((ext_vector_type(8))) unsigned short ushort8v;
typedef __attribute__((ext_vector_type(4))) float f32x4;

#define B_  4
#define T_  2048
#define E_  1024
#define H_  16
#define D_  64
#define HD_ 1024
#define BT_ (B_*T_)
#define TC_ 64                 // scan chunk length
#define NC_ (T_/TC_)           // 32 chunks
#define SG_ 32                 // score e-groups (SEB = E/SG = 32)
#define SEB_ (E_/SG_)
#define SHB_ 2                 // h's per score block -> 2048 score blocks

__device__ __forceinline__ u16 f2b(float f) {
  uint32_t u = __float_as_uint(f);
  uint32_t r = (u + 0x7FFFu + ((u >> 16) & 1u)) >> 16;   // RNE, inputs never NaN
  return (u16)r;
}
__device__ __forceinline__ float b2f(u16 u) {
  return __uint_as_float(((uint32_t)u) << 16);
}

// ---------------------------------------------------------------------------
// P: fused prep. blocks [0,2048): x -> xb bf16 + xTb8 (x^T in [b][e/8][t][8e]).
// blocks [2048,2560): the two 1024x1024 weight transposes (f32 -> bf16^T).
// ---------------------------------------------------------------------------
__global__ __launch_bounds__(256) void prep_all(const float* __restrict__ x,
                                                const float* __restrict__ wv,
                                                const float* __restrict__ wo,
                                                u16* __restrict__ xb,
                                                u16* __restrict__ xTb8,
                                                u16* __restrict__ wvT,
                                                u16* __restrict__ woT) {
  __shared__ float tile[64][65];
  const int bid = blockIdx.x;
  if (bid < 2048) {
    const int b = bid >> 9, rest = bid & 511;
    const int t0 = (rest >> 4) * 64, e0 = (rest & 15) * 64;
    const int c4 = (threadIdx.x & 15) * 4;    // 0..60
    const int rw = threadIdx.x >> 4;          // 0..15
#pragma unroll
    for (int r = 0; r < 4; ++r) {
      const int row = r * 16 + rw;            // t-local
      const float4 v4 = *reinterpret_cast<const float4*>(
          &x[((size_t)b * T_ + t0 + row) * E_ + e0 + c4]);
      tile[row][c4 + 0] = v4.x; tile[row][c4 + 1] = v4.y;
      tile[row][c4 + 2] = v4.z; tile[row][c4 + 3] = v4.w;
      ushort4 o;
      o.x = f2b(v4.x); o.y = f2b(v4.y); o.z = f2b(v4.z); o.w = f2b(v4.w);
      *reinterpret_cast<ushort4*>(&xb[((size_t)(b * T_ + t0 + row)) * E_ + e0 + c4]) = o;
    }
    __syncthreads();
    const int tl = threadIdx.x & 63;          // t-local
    const int eg = threadIdx.x >> 6;          // 0..3
#pragma unroll
    for (int p = 0; p < 2; ++p) {
      const int egg = eg + p * 4;             // e-group 0..7 (8 e's each)
      ushort8v o;
#pragma unroll
      for (int j = 0; j < 8; ++j) o[j] = f2b(tile[tl][egg * 8 + j]);
      *reinterpret_cast<ushort8v*>(
          &xTb8[((size_t)(b * (E_ / 8) + (e0 >> 3) + egg) * T_ + t0 + tl) * 8]) = o;
    }
  } else {
    const int k = bid - 2048;
    const float* in = (k >> 8) ? wo : wv;
    u16* out = (k >> 8) ? woT : wvT;
    const int r0 = ((k >> 4) & 15) * 64, c0 = (k & 15) * 64;
    const int tx = threadIdx.x & 63, ty = threadIdx.x >> 6;
#pragma unroll
    for (int r = 0; r < 16; ++r) {
      int row = r * 4 + ty;
      tile[row][tx] = in[(size_t)(r0 + row) * 1024 + c0 + tx];
    }
    __syncthreads();
#pragma unroll
    for (int r = 0; r < 16; ++r) {
      int row = r * 4 + ty;
      out[(size_t)(c0 + row) * 1024 + r0 + tx] = f2b(tile[tx][row]);
    }
  }
}

// ---------------------------------------------------------------------------
// GEMM: C[M][N] = A[M][K] * Bt[N][K]^T, bf16 in, f32 accum.  (R13/R16 version
// — best measured.) 128x128 tile, BK=64, double-buffered LDS with STAGE(kt+1)
// issued BEFORE ds_read+MFMA of tile kt; one __syncthreads per K-step.
// T2 XOR swizzle (both-sides), gload_lds w16, XCD swizzle, setprio.
// ---------------------------------------------------------------------------
template <int OUT_BF16>
__global__ __launch_bounds__(256) void gemm_bt(const u16* __restrict__ A,
                                               const u16* __restrict__ Bt,
                                               float* __restrict__ Cf,
                                               u16* __restrict__ Cb,
                                               int M, int N, int K) {
  __shared__ __align__(16) u16 As[2][128 * 64];
  __shared__ __align__(16) u16 Bs[2][128 * 64];
  const int tid  = threadIdx.x;
  const int lane = tid & 63;
  const int wave = tid >> 6;
  const int wr_  = wave >> 1, wc_ = wave & 1;

  const int nwg = gridDim.x * gridDim.y;
  const int bid = blockIdx.y * gridDim.x + blockIdx.x;
  const int cpx = nwg >> 3;
  const int swz = (bid & 7) * cpx + (bid >> 3);
  const int bx = swz % gridDim.x, by = swz / gridDim.x;
  const int brow = by * 128;
  const int bcol = bx * 128;
  const int l15 = lane & 15, l4 = lane >> 4;

  f32x4 acc[4][4];
  const f32x4 zero = {0.f, 0.f, 0.f, 0.f};
#pragma unroll
  for (int i = 0; i < 4; ++i)
#pragma unroll
    for (int j = 0; j < 4; ++j) acc[i][j] = zero;

  // stage K-tile kt into buffer buf (8 gload_lds/thread, inverse-swizzled src)
  auto stage = [&](int kt, int buf) {
    const int k0 = kt * 64;
#pragma unroll
    for (int s2 = 0; s2 < 4; ++s2) {
      const int c = s2 * 256 + tid;             // 16B chunk id 0..1023
      const int row = c >> 3, g = c & 7;        // 8 chunks per 128B row
      const int gs = g ^ (row & 7);             // inverse-swizzled SOURCE granule
      const u16* ga = A  + (size_t)(brow + row) * K + k0 + gs * 8;
      const u16* gb = Bt + (size_t)(bcol + row) * K + k0 + gs * 8;
      u16* la = &As[buf][(size_t)(s2 * 256 + wave * 64) * 8];  // wave-uniform base
      u16* lb = &Bs[buf][(size_t)(s2 * 256 + wave * 64) * 8];
      __builtin_amdgcn_global_load_lds((const __attribute__((address_space(1))) void*)ga,
                                       (__attribute__((address_space(3))) void*)la,
                                       16, 0, 0);
      __builtin_amdgcn_global_load_lds((const __attribute__((address_space(1))) void*)gb,
                                       (__attribute__((address_space(3))) void*)lb,
                                       16, 0, 0);
    }
  };

  const int NK = K / 64;                        // 16
  stage(0, 0);
  __syncthreads();                              // buf0 ready

  int cur = 0;
  for (int kt = 0; kt < NK; ++kt) {
    if (kt + 1 < NK) stage(kt + 1, cur ^ 1);    // issue next tile FIRST

    short8 af[2][4], bfr[2][4];
#pragma unroll
    for (int kk = 0; kk < 2; ++kk) {
      const int sg = (kk * 4 + l4) ^ (l15 & 7); // swizzled read granule
#pragma unroll
      for (int mi = 0; mi < 4; ++mi)
        af[kk][mi] = *reinterpret_cast<const short8*>(
            &As[cur][(wr_ * 64 + mi * 16 + l15) * 64 + sg * 8]);
#pragma unroll
      for (int ni = 0; ni < 4; ++ni)
        bfr[kk][ni] = *reinterpret_cast<const short8*>(
            &Bs[cur][(wc_ * 64 + ni * 16 + l15) * 64 + sg * 8]);
    }
    __builtin_amdgcn_s_setprio(1);
#pragma unroll
    for (int kk = 0; kk < 2; ++kk)
#pragma unroll
      for (int mi = 0; mi < 4; ++mi)
#pragma unroll
        for (int ni = 0; ni < 4; ++ni)
          acc[mi][ni] = __builtin_amdgcn_mfma_f32_16x16x32_bf16(af[kk][mi], bfr[kk][ni],
                                                                acc[mi][ni], 0, 0, 0);
    __builtin_amdgcn_s_setprio(0);
    __syncthreads();                            // drains vmcnt -> next buf ready;
    cur ^= 1;                                   // also protects buf[cur] reuse
  }

#pragma unroll
  for (int mi = 0; mi < 4; ++mi) {
#pragma unroll
    for (int ni = 0; ni < 4; ++ni) {
      const int col = bcol + wc_ * 64 + ni * 16 + l15;
#pragma unroll
      for (int j = 0; j < 4; ++j) {
        const int row = brow + wr_ * 64 + mi * 16 + l4 * 4 + j;
        if (OUT_BF16) Cb[(size_t)row * N + col] = f2b(acc[mi][ni][j]);
        else          Cf[(size_t)row * N + col] = acc[mi][ni][j];
      }
    }
  }
}

// ---------------------------------------------------------------------------
// K2a: partial[g][b][h][t] (bf16) = sum_{e in g} x[b,t,e]*wr[h,e,t] / 8.
// XCD-coherent block decode (bijective): the 8 h-group blocks that share an
// xTb8 slice are ADJACENT ON THE SAME XCD (lid&7 = xcd; hz in next 3 bits),
// so x is read once/HBM + 7x/L2 instead of 8x/HBM. (t,g) pairs partition
// exclusively across XCDs. Pure index remap — no correctness surface.
// ---------------------------------------------------------------------------
__global__ __launch_bounds__(256) void score_partial(const u16* __restrict__ xTb8,
                                                     const float* __restrict__ wr,
                                                     u16* __restrict__ partial) {
  const int lid    = blockIdx.x;                // 0..2047
  const int xcd    = lid & 7;
  const int within = lid >> 3;                  // 0..255
  const int hz     = within & 7;                // 0..7 (adjacent per (t,g))
  const int pair   = xcd * 32 + (within >> 3);  // 0..255, XCD-exclusive
  const int t  = (pair >> 5) * 256 + threadIdx.x;
  const int g  = pair & 31;
  const int h0 = hz * SHB_;

  float acc[4][SHB_];                           // [b][hh]
#pragma unroll
  for (int b = 0; b < 4; ++b)
#pragma unroll
    for (int hh = 0; hh < SHB_; ++hh) acc[b][hh] = 0.f;

#pragma unroll
  for (int e8 = 0; e8 < SEB_ / 8; ++e8) {       // 4 iters of 8 e's
    const int eb = g * (SEB_ / 8) + e8;         // e-group index
    ushort8v xv[4];
#pragma unroll
    for (int b = 0; b < 4; ++b)
      xv[b] = *reinterpret_cast<const ushort8v*>(
          &xTb8[((size_t)(b * (E_ / 8) + eb) * T_ + t) * 8]);
#pragma unroll
    for (int j = 0; j < 8; ++j) {
      const int e = eb * 8 + j;
      float xf[4];
#pragma unroll
      for (int b = 0; b < 4; ++b) xf[b] = b2f(xv[b][j]);
#pragma unroll
      for (int hh = 0; hh < SHB_; ++hh) {
        const float w = wr[((size_t)(h0 + hh) * E_ + e) * T_ + t];
#pragma unroll
        for (int b = 0; b < 4; ++b) acc[b][hh] = fmaf(xf[b], w, acc[b][hh]);
      }
    }
  }
  u16* pp = partial + (size_t)g * (B_ * H_ * T_);
#pragma unroll
  for (int b = 0; b < 4; ++b)
#pragma unroll
    for (int hh = 0; hh < SHB_; ++hh)
      pp[((size_t)b * H_ + h0 + hh) * T_ + t] = f2b(acc[b][hh] * 0.125f);
}

// ---------------------------------------------------------------------------
// K3a (fused reduce): lane t sums the 32 bf16 partials -> s value; writes s
// for chunk_scan; wave-local LDS broadcast. Then per-chunk max + sums.
// ---------------------------------------------------------------------------
__global__ __launch_bounds__(256) void chunk_sums(const u16* __restrict__ partial,
                                                  const u16* __restrict__ v,
                                                  float* __restrict__ s,
                                                  float* __restrict__ sev,
                                                  float* __restrict__ se,
                                                  float* __restrict__ mc) {
  const int bh = blockIdx.y;
  const int b = bh >> 4, h = bh & 15;
  const int w = threadIdx.x >> 6, d = threadIdx.x & 63;
  const int c = blockIdx.x * 4 + w;
  const int t = blockIdx.x * 256 + threadIdx.x;   // == c*64 + d

  float sv = 0.f;
#pragma unroll
  for (int g = 0; g < SG_; ++g)
    sv += b2f(partial[(size_t)g * (B_ * H_ * T_) + (size_t)bh * T_ + t]);
  s[(size_t)bh * T_ + t] = sv;

  __shared__ float es[4][64];
  es[w][d] = sv;                                  // wave-local, no barrier needed

  float lm = sv;                                  // chunk max
#pragma unroll
  for (int off = 1; off < 64; off <<= 1) lm = fmaxf(lm, __shfl_xor(lm, off, 64));

  const u16* vp = v + ((size_t)(b * T_ + c * TC_)) * HD_ + h * D_ + d;
  float acc = 0.f, ae = 0.f;
#pragma unroll 8
  for (int tt = 0; tt < TC_; ++tt) {
    float e = __expf(es[w][tt] - lm);
    acc = fmaf(e, b2f(vp[(size_t)tt * HD_]), acc);
    ae += e;
  }
  sev[((size_t)bh * NC_ + c) * D_ + d] = acc;
  if (d == 0) { se[bh * NC_ + c] = ae; mc[bh * NC_ + c] = lm; }
}

// ---------------------------------------------------------------------------
// K3c: global max; prefix from rescaled chunk totals; inclusive rescan.
// ---------------------------------------------------------------------------
__global__ __launch_bounds__(256) void chunk_scan(const float* __restrict__ s,
                                                  const u16* __restrict__ v,
                                                  const float* __restrict__ sev,
                                                  const float* __restrict__ se,
                                                  const float* __restrict__ mc,
                                                  u16* __restrict__ attn) {
  const int bh = blockIdx.y;
  const int b = bh >> 4, h = bh & 15;
  const int w = threadIdx.x >> 6, d = threadIdx.x & 63;
  const int c = blockIdx.x * 4 + w;
  const float* mcp = mc + bh * NC_;

  float gm = (d < NC_) ? mcp[d] : -1e30f;
#pragma unroll
  for (int off = 1; off < 64; off <<= 1) gm = fmaxf(gm, __shfl_xor(gm, off, 64));

  const float* sevp = sev + (size_t)bh * NC_ * D_;
  const float* sep  = se + bh * NC_;
  float pn = 0.f, pd = 0.f;
  for (int c2 = 0; c2 < c; ++c2) {
    float f = __expf(mcp[c2] - gm);
    pn = fmaf(sevp[(size_t)c2 * D_ + d], f, pn);
    pd = fmaf(sep[c2], f, pd);
  }

  const float* sp = s + (size_t)bh * T_ + c * TC_;
  const u16* vp = v + ((size_t)(b * T_ + c * TC_)) * HD_ + h * D_ + d;
  u16* ap = attn + ((size_t)(b * T_ + c * TC_)) * HD_ + h * D_ + d;
#pragma unroll 8
  for (int tt = 0; tt < TC_; ++tt) {
    float e = __expf(sp[tt] - gm);
    pn = fmaf(e, b2f(vp[(size_t)tt * HD_]), pn);
    pd += e;
    ap[(size_t)tt * HD_] = f2b(__fdividef(pn, pd));
  }
}

// ---------------------------------------------------------------------------
extern "C" void kernel_launch(void* const* d_in, const int* in_sizes, int n_in,
                              void* d_out, int out_size, void* d_ws, size_t ws_size,
                              hipStream_t stream) {
  const float* x  = (const float*)d_in[0];
  const float* wv = (const float*)d_in[1];
  const float* wr = (const float*)d_in[2];
  const float* wo = (const float*)d_in[3];
  float* out = (float*)d_out;

  char* ws = (char*)d_ws;
  size_t off = 0;
  auto alloc = [&](size_t bytes) {
    void* p = ws + off;
    off += (bytes + 255) & ~(size_t)255;
    return p;
  };
  u16*   xb   = (u16*)  alloc((size_t)BT_ * E_ * 2);
  u16*   xTb8 = (u16*)  alloc((size_t)B_ * E_ * T_ * 2);
  u16*   wvT  = (u16*)  alloc((size_t)HD_ * E_ * 2);
  u16*   woT  = (u16*)  alloc((size_t)E_ * HD_ * 2);
  u16*   vv   = (u16*)  alloc((size_t)BT_ * HD_ * 2);
  u16*   attn = (u16*)  alloc((size_t)BT_ * HD_ * 2);
  float* s    = (float*)alloc((size_t)B_ * H_ * T_ * 4);
  float* sev  = (float*)alloc((size_t)B_ * H_ * NC_ * D_ * 4);
  float* se   = (float*)alloc((size_t)B_ * H_ * NC_ * 4);
  float* mc   = (float*)alloc((size_t)B_ * H_ * NC_ * 4);
  u16*   part = (u16*)  alloc((size_t)SG_ * B_ * H_ * T_ * 2);   // 8 MB bf16

  prep_all<<<2560, 256, 0, stream>>>(x, wv, wo, xb, xTb8, wvT, woT);

  // v = xb @ wv  (bf16 out)
  gemm_bt<1><<<dim3(HD_ / 128, BT_ / 128), 256, 0, stream>>>(xb, wvT, nullptr, vv, BT_, HD_, E_);

  score_partial<<<2048, 256, 0, stream>>>(xTb8, wr, part);

  chunk_sums<<<dim3(NC_ / 4, B_ * H_), 256, 0, stream>>>(part, vv, s, sev, se, mc);
  chunk_scan<<<dim3(NC_ / 4, B_ * H_), 256, 0, stream>>>(s, vv, sev, se, mc, attn);

  // out = attn @ wo  (f32 out)
  gemm_bt<0><<<dim3(E_ / 128, BT_ / 128), 256, 0, stream>>>(attn, woT, out, nullptr, BT_, E_, HD_);
}